// Round 12
// baseline (69.365 us; speedup 1.0000x reference)
//
#include <hip/hip_runtime.h>

constexpr int Tn = 512;       // seq len
constexpr int Bn = 4096;      // batch
constexpr int CH = 32;        // timesteps per chunk
constexpr int NCH = Tn / CH;  // 16

// Gates are computed PRE-SCALED by folding these into weights/biases:
// i,f,o by -log2e (sigmoid), g by +2*log2e (tanh). Cell state c is carried
// scaled by +2*log2e so exp2(c_s) needs no multiply.
constexpr float NL2E = -1.44269504088896340736f;
constexpr float P2L2E = 2.88539008177792681472f;

typedef float f4 __attribute__((ext_vector_type(4)));

#if defined(__has_builtin)
#if __has_builtin(__builtin_amdgcn_exp2f)
#define EXP2F(x) __builtin_amdgcn_exp2f(x)
#else
#define EXP2F(x) exp2f(x)
#endif
#else
#define EXP2F(x) exp2f(x)
#endif

// row_shr:1 within 16-lane rows: dst[i] = src[i-1]; lane0 of row keeps old.
__device__ __forceinline__ float dpp_shr1(float v) {
  return __int_as_float(__builtin_amdgcn_update_dpp(
      __float_as_int(v), __float_as_int(v), 0x111, 0xf, 0xf, false));
}

// One LSTM pipeline tick: 5 exp2 + 2 rcp.
//   - inner gate fma depends only on h -> runs parallel with dpp_shr1(h)
//   - c' = [c*P + 2l2e*(Eg-1)*Q] * rcp(Q*P)            (scaled cell)
//   - h  = (Ec-1) * rcp((1+Eo)*(1+Ec)), Ec=2^min(c',80) (clamp keeps finite)
template <bool GATED>
__device__ __forceinline__ void tick(float& h, float& c, const float4 pre,
                                     const float4 wih, const float4 whh,
                                     unsigned tau, unsigned lg) {
  const float h_in = dpp_shr1(h);            // || with the t* fmas below
  const float tg = fmaf(h, whh.z, pre.z);    // depend only on h
  const float ti = fmaf(h, whh.x, pre.x);
  const float tf = fmaf(h, whh.y, pre.y);
  const float to = fmaf(h, whh.w, pre.w);
  const float ag = fmaf(h_in, wih.z, tg);    // 2l2e*z_g (critical gate)
  const float ai = fmaf(h_in, wih.x, ti);    // -l2e*z_i
  const float af = fmaf(h_in, wih.y, tf);    // -l2e*z_f
  const float ao = fmaf(h_in, wih.w, to);    // -l2e*z_o
  const float Eg = EXP2F(ag);                // critical gate first
  const float Ei = EXP2F(ai);
  const float Ef = EXP2F(af);
  const float Eo = EXP2F(ao);
  const float v = 1.0f + Eg;
  const float u = 1.0f + Ei;
  const float Q = 1.0f + Ef;
  const float P = u * v;
  const float QP = Q * P;
  const float R = __builtin_amdgcn_rcpf(QP);
  const float ws = fmaf(P2L2E, Eg, -P2L2E);  // 2l2e*(Eg-1)
  const float num = fmaf(c, P, ws * Q);      // overlaps rcp
  const float cn = num * R;                  // new scaled cell
  const float Ec = EXP2F(fminf(cn, 80.0f));  // clamp keeps products finite
  const float so = 1.0f + Eo;
  const float t2 = 1.0f + Ec;
  const float R2 = __builtin_amdgcn_rcpf(so * t2);
  const float hn = (Ec - 1.0f) * R2;
  if (GATED) {
    const bool act = (tau - lg) < (unsigned)Tn;  // unsigned wrap: tau<lg off
    c = act ? cn : c;
    h = act ? hn : h;
  } else {
    c = cn;
    h = hn;
  }
}

// Fused: layer-0 projection (streaming x) + 6-layer DPP-pipelined recurrence.
// 512 single-wave blocks. Pre-masked LDS addressing (R11). PROJ/LOADC work
// is WOVEN between consecutive ticks so it fills dependency-stall bubbles.
__global__ __launch_bounds__(64, 1) void lstm_fused_kernel(
    const float* __restrict__ x, const float* __restrict__ w_ih0,
    const float* __restrict__ w_ih_rest, const float* __restrict__ w_hh,
    const float* __restrict__ b_ih, const float* __restrict__ b_hh,
    float* __restrict__ out) {
  __shared__ __align__(16) float4 bufA[CH * 8];    // [t_local][elem]
  __shared__ __align__(16) float4 bufB[CH * 8];
  __shared__ __align__(16) float4 biasRep[32 * 8]; // [row][lg] = bz(lg)

  const int ln = threadIdx.x;
  const int bW = blockIdx.x * 8;  // wave's batch base
  // tick-phase roles
  const int ge = ln >> 3;         // batch element (group) 0..7
  const unsigned lg = ln & 7;     // pipeline lane = layer for lg<6
  const bool is0l = (lg == 0);
  // proj-phase roles
  const int ep = ln & 7;          // element
  const int t8p = ln >> 3;        // t sub-index 0..7

  // ---- per-lane recurrence weights (pre-scaled) ----
  const int l = (lg < 6) ? (int)lg : 5;
  float4 whh = make_float4(NL2E * w_hh[l * 4 + 0], NL2E * w_hh[l * 4 + 1],
                           P2L2E * w_hh[l * 4 + 2], NL2E * w_hh[l * 4 + 3]);
  float4 wih = make_float4(0.f, 0.f, 0.f, 0.f);
  float4 bz = make_float4(0.f, 0.f, 0.f, 0.f);  // non-leader gate bias (scaled)
  if (lg >= 1 && lg < 6) {
    wih = make_float4(NL2E * w_ih_rest[(l - 1) * 4 + 0],
                      NL2E * w_ih_rest[(l - 1) * 4 + 1],
                      P2L2E * w_ih_rest[(l - 1) * 4 + 2],
                      NL2E * w_ih_rest[(l - 1) * 4 + 3]);
    bz = make_float4(NL2E * (b_ih[lg * 4 + 0] + b_hh[lg * 4 + 0]),
                     NL2E * (b_ih[lg * 4 + 1] + b_hh[lg * 4 + 1]),
                     P2L2E * (b_ih[lg * 4 + 2] + b_hh[lg * 4 + 2]),
                     NL2E * (b_ih[lg * 4 + 3] + b_hh[lg * 4 + 3]));
  }
  if (lg >= 6) whh = make_float4(0.f, 0.f, 0.f, 0.f);  // inert lanes

  // ---- fill the replicated bias region: row r, slot lg -> bz(lg) ----
#pragma unroll
  for (int rep = 0; rep < 4; ++rep) biasRep[rep * 64 + ln] = bz;

  // per-lane read bases: leader walks the projection tile, others the bias
  // region; both consumed with the same immediate offsets (jb*8+k)*128.
  const char* rbA = is0l ? (const char*)(bufA + ge) : (const char*)(biasRep + (int)lg);
  const char* rbB = is0l ? (const char*)(bufB + ge) : (const char*)(biasRep + (int)lg);

  // ---- layer-0 projection weights, pre-scaled, transposed for pk-fma ----
  // wv[d] = (sc_g * w_ih0[g*16+d]) over g=0..3
  f4 wv[16], pbv;
  {
    const float sc[4] = {NL2E, NL2E, P2L2E, NL2E};
#pragma unroll
    for (int d = 0; d < 16; ++d)
      wv[d] = (f4){sc[0] * w_ih0[0 * 16 + d], sc[1] * w_ih0[1 * 16 + d],
                   sc[2] * w_ih0[2 * 16 + d], sc[3] * w_ih0[3 * 16 + d]};
    pbv = (f4){sc[0] * (b_ih[0] + b_hh[0]), sc[1] * (b_ih[1] + b_hh[1]),
               sc[2] * (b_ih[2] + b_hh[2]), sc[3] * (b_ih[3] + b_hh[3])};
  }

  const float4* x4 = (const float4*)x;
  float4 xs[16];
  float h = 0.f, c = 0.f;
  float4 pA[8], pB[8];

  // full-chunk x load (prologue only)
  auto LOADC = [&](int ci) {
    const size_t base = ((size_t)(bW + ep) * Tn + (size_t)ci * CH + t8p) * 4;
#pragma unroll
    for (int k = 0; k < 4; ++k)
#pragma unroll
      for (int i = 0; i < 4; ++i) xs[k * 4 + i] = x4[base + (size_t)k * 32 + i];
  };
  // one 16-fma sub of projection quarter qk (a-component i), pk-vectorized
  auto PROJsub = [&](f4& sv, int qk, int i) {
    const float4 a = xs[qk * 4 + i];
    sv = __builtin_elementwise_fma((f4){a.x, a.x, a.x, a.x}, wv[i * 4 + 0], sv);
    sv = __builtin_elementwise_fma((f4){a.y, a.y, a.y, a.y}, wv[i * 4 + 1], sv);
    sv = __builtin_elementwise_fma((f4){a.z, a.z, a.z, a.z}, wv[i * 4 + 2], sv);
    sv = __builtin_elementwise_fma((f4){a.w, a.w, a.w, a.w}, wv[i * 4 + 3], sv);
  };
  // full projection quarter (prologue only)
  auto PROJq = [&](float4* dst, int qk) {
    f4 sv = pbv;
#pragma unroll
    for (int i = 0; i < 4; ++i) PROJsub(sv, qk, i);
    *(f4*)&dst[ln + 64 * qk] = sv;
  };
  // bulk LDS->reg for one 8-tick block: per-lane base + uniform imm offsets;
  // result IS the final gate base (pre-masked addressing).
  auto RD = [&](float4* p, const char* b, int jb) {
#pragma unroll
    for (int k = 0; k < 8; ++k)
      p[k] = *(const float4*)(b + (size_t)((jb * 8 + k) * 128));
  };
  // 8 ticks, optionally with woven side work:
  //   MODE 0: plain; MODE 1: + PROJ quarter qk -> dst (subs at k=0..3);
  //   MODE 2: MODE 1 + LOADC of chunk ci (4 loads/tick at k=4..7)
  auto T8W = [&](float4* p, int MODE, float4* dst, int qk, int ci) {
    f4 sv = pbv;
    size_t lbase = 0;
    if (MODE == 2)
      lbase = ((size_t)(bW + ep) * Tn + (size_t)ci * CH + t8p) * 4;
#pragma unroll
    for (int k = 0; k < 8; ++k) {
      tick<false>(h, c, p[k], wih, whh, 0u, 0u);
      if (MODE >= 1 && k < 4) {
        PROJsub(sv, qk, k);
        if (k == 3) *(f4*)&dst[ln + 64 * qk] = sv;
      }
      if (MODE == 2 && k >= 4) {
        const int m = k - 4;
#pragma unroll
        for (int i = 0; i < 4; ++i)
          xs[m * 4 + i] = x4[lbase + (size_t)m * 32 + i];
      }
    }
  };
  // gated 8 ticks (pipeline fill) with woven PROJ quarter
  auto T8Wg = [&](float4* p, float4* dst, int qk, unsigned tau0) {
    f4 sv = pbv;
#pragma unroll
    for (int k = 0; k < 8; ++k) {
      tick<true>(h, c, p[k], wih, whh, tau0 + (unsigned)k, lg);
      if (k < 4) {
        PROJsub(sv, qk, k);
        if (k == 3) *(f4*)&dst[ln + 64 * qk] = sv;
      }
    }
  };

  // ---- prologue: chunk 0 -> bufA (plain); chunk 1 x in regs ----
  LOADC(0);
#pragma unroll
  for (int k = 0; k < 4; ++k) PROJq(bufA, k);
  LOADC(1);
  RD(pA, rbA, 0);

  // ---- chunk 0: block 0 gated; weave PROJ(chunk1)->bufB, LOADC(2) ----
  RD(pB, rbA, 1);  T8Wg(pA, bufB, 0, 0u);
  RD(pA, rbA, 2);  T8W(pB, 1, bufB, 1, 0);
  RD(pB, rbA, 3);  T8W(pA, 1, bufB, 2, 0);
  RD(pA, rbB, 0);  T8W(pB, 2, bufB, 3, 2);

  // ---- chunks 1..15 (entry invariant: pA holds block 0 of chunk j) ----
#pragma unroll 1
  for (int j = 1; j < NCH; ++j) {
    const char* rc = (j & 1) ? rbB : rbA;
    const char* rn = (j & 1) ? rbA : rbB;
    float4* bn = (j & 1) ? bufA : bufB;
    const int m1 = (j < NCH - 1) ? 1 : 0;  // PROJ next chunk?
    RD(pB, rc, 1);  T8W(pA, m1, bn, 0, 0);
    RD(pA, rc, 2);  T8W(pB, m1, bn, 1, 0);
    RD(pB, rc, 3);  T8W(pA, m1, bn, 2, 0);
    const int m3 = (j < NCH - 2) ? 2 : m1; // + LOADC j+2?
    RD(pA, (j < NCH - 1) ? rn : rc, 0);
    T8W(pB, m3, bn, 3, j + 2);
  }

  // ---- tail: 5 gated ticks (tau=512..516); leaders inactive, pre=bz ----
#pragma unroll
  for (unsigned k = 0; k < 5; ++k)
    tick<true>(h, c, bz, wih, whh, 512u + k, lg);

  if (lg == 5) out[bW + ge] = h;  // H=1: hidden channel 0 == h
}

extern "C" void kernel_launch(void* const* d_in, const int* in_sizes, int n_in,
                              void* d_out, int out_size, void* d_ws, size_t ws_size,
                              hipStream_t stream) {
  (void)in_sizes; (void)n_in; (void)out_size; (void)d_ws; (void)ws_size;
  const float* x         = (const float*)d_in[0];
  const float* w_ih0     = (const float*)d_in[1];
  const float* w_ih_rest = (const float*)d_in[2];
  const float* w_hh      = (const float*)d_in[3];
  const float* b_ih      = (const float*)d_in[4];
  const float* b_hh      = (const float*)d_in[5];
  float* out = (float*)d_out;

  lstm_fused_kernel<<<Bn / 8, 64, 0, stream>>>(x, w_ih0, w_ih_rest, w_hh,
                                               b_ih, b_hh, out);
}

// Round 13
// 45.903 us; speedup vs baseline: 1.5111x; 1.5111x over previous
//
#include <hip/hip_runtime.h>

constexpr int Tn = 512;       // seq len
constexpr int Bn = 4096;      // batch
constexpr int CH = 32;        // timesteps per chunk
constexpr int NCH = Tn / CH;  // 16

// Gates are PRE-SCALED by folding into weights/biases: i,f,o by -log2e
// (sigmoid), g by +2*log2e (tanh). Cell c is carried scaled by +2*log2e.
constexpr float NL2E = -1.44269504088896340736f;
constexpr float P2L2E = 2.88539008177792681472f;

#if defined(__has_builtin)
#if __has_builtin(__builtin_amdgcn_exp2f)
#define EXP2F(x) __builtin_amdgcn_exp2f(x)
#else
#define EXP2F(x) exp2f(x)
#endif
#else
#define EXP2F(x) exp2f(x)
#endif

// quad_perm [0,0,2,2]: both lanes of a pair get the EVEN lane's value
__device__ __forceinline__ float dpp_pair_even(float v) {
  return __int_as_float(__builtin_amdgcn_update_dpp(
      __float_as_int(v), __float_as_int(v), 0xA0, 0xf, 0xf, false));
}
// quad_perm [1,1,3,3]: both lanes of a pair get the ODD lane's value
__device__ __forceinline__ float dpp_pair_odd(float v) {
  return __int_as_float(__builtin_amdgcn_update_dpp(
      __float_as_int(v), __float_as_int(v), 0xF5, 0xf, 0xf, false));
}
// row_shr:2 within 16-lane rows: lane i <- lane i-2 (lanes 0,1 keep old)
__device__ __forceinline__ float dpp_shr2(float v) {
  return __int_as_float(__builtin_amdgcn_update_dpp(
      __float_as_int(v), __float_as_int(v), 0x112, 0xf, 0xf, false));
}

// One LSTM tick, cell split across a lane pair. Even lane: gates A=i, B=g,
// owns c/h. Odd lane: A=f, B=o (its c/h are garbage, never consumed).
//   c'_s = [c_s*P + 2l2e*(Eg-1)*Q] * rcp(Q*P)   (P=(1+Ei)(1+Eg), Q=1+Ef)
//   h    = sig_o * (1 - 2*rcp(1+2^c'_s)),  sig_o = rcp(1+Eo) from odd lane
// One shared rcp instr: even feeds Q*P, odd feeds 1+Eo (lane-select input).
template <bool GATED>
__device__ __forceinline__ void tick(float& h, float& c, const float2 pre,
                                     const float2 wih, const float2 whh,
                                     bool podd, unsigned tau, unsigned l) {
  const float hb = dpp_pair_even(h);     // h_l(t-1) shared to pair
  const float h_in = dpp_shr2(hb);       // h_{l-1}(t) from previous pair
  const float tA = fmaf(hb, whh.x, pre.x);
  const float tB = fmaf(hb, whh.y, pre.y);
  const float aA = fmaf(h_in, wih.x, tA);   // even: -l2e*z_i ; odd: -l2e*z_f
  const float aB = fmaf(h_in, wih.y, tB);   // even: 2l2e*z_g ; odd: -l2e*z_o
  const float EA = EXP2F(aA);
  const float EB = EXP2F(aB);
  const float sA = 1.0f + EA;            // even: u=1+Ei ; odd: Q=1+Ef
  const float sB = 1.0f + EB;            // even: v=1+Eg ; odd: 1+Eo
  const float m = sA * sB;               // even: P
  const float Qx = dpp_pair_odd(sA);     // Q to both lanes
  const float qm = Qx * m;               // even: Q*P
  const float rin = podd ? sB : qm;
  const float RC = __builtin_amdgcn_rcpf(rin);  // even: R ; odd: sig_o
  const float sgo = dpp_pair_odd(RC);    // sig_o to both lanes
  const float ws = fmaf(P2L2E, EB, -P2L2E);  // even: 2l2e*(Eg-1)
  const float wsQ = ws * Qx;
  const float num = fmaf(c, m, wsQ);     // even: c*P + ws*Q
  const float cn = num * RC;             // even: new scaled cell
  const float Ec = EXP2F(cn);            // Inf-safe: Ec=Inf -> th -> 1
  const float t2 = 1.0f + Ec;
  const float rt = __builtin_amdgcn_rcpf(t2);
  const float th = fmaf(-2.0f, rt, 1.0f);  // tanh(c)
  const float hn = sgo * th;
  if (GATED) {
    const bool act = (tau - l) < (unsigned)Tn;  // unsigned wrap: tau<l off
    c = act ? cn : c;
    h = act ? hn : h;
  } else {
    c = cn;
    h = hn;
  }
}

// Fused layer-0 projection + 6-layer systolic recurrence, 16 lanes/element
// (lane pair per layer). 1024 single-wave blocks -> 4 blocks/CU, all SIMDs.
// LDS: unified [2][32 rows][64 slots] float2; slot=lane. Leader-pair slots
// hold projections (rewritten per chunk); all other slots hold that lane's
// replicated gate bias (written once) -> 1 ds_read_b64/tick, no mask ops.
__global__ __launch_bounds__(64, 1) void lstm_fused_kernel(
    const float* __restrict__ x, const float* __restrict__ w_ih0,
    const float* __restrict__ w_ih_rest, const float* __restrict__ w_hh,
    const float* __restrict__ b_ih, const float* __restrict__ b_hh,
    float* __restrict__ out) {
  __shared__ __align__(16) float2 buf[2][CH][64];  // 32 KB

  const int ln = threadIdx.x;
  const int bW = blockIdx.x * 4;   // 4 elements per wave
  // tick-phase roles
  const int eT = ln >> 4;          // element (16-lane row)
  const int rlane = ln & 15;
  const unsigned l = (unsigned)(rlane >> 1);  // layer (active l<6)
  const bool podd = (rlane & 1) != 0;
  // proj-phase roles
  const int eP = ln & 3;           // element
  const int tq = ln >> 2;          // t sub-index 0..15

  // ---- per-lane recurrence weights (pre-scaled) ----
  const int lc = (l < 6) ? (int)l : 5;
  const int gA = podd ? 1 : 0;     // even: i, odd: f   (both -l2e scale)
  const int gB = podd ? 3 : 2;     // even: g (+2l2e), odd: o (-l2e)
  const float scB = podd ? NL2E : P2L2E;
  float2 whh = make_float2(NL2E * w_hh[lc * 4 + gA], scB * w_hh[lc * 4 + gB]);
  float2 wih = make_float2(0.f, 0.f);
  float2 bz = make_float2(0.f, 0.f);
  if (l >= 1 && l < 6) {
    wih = make_float2(NL2E * w_ih_rest[(lc - 1) * 4 + gA],
                      scB * w_ih_rest[(lc - 1) * 4 + gB]);
    bz = make_float2(NL2E * (b_ih[l * 4 + gA] + b_hh[l * 4 + gA]),
                     scB * (b_ih[l * 4 + gB] + b_hh[l * 4 + gB]));
  }
  if (l >= 6) whh = make_float2(0.f, 0.f);  // inert lanes

  // ---- bias fill: every row of both buffers, own slot (once) ----
#pragma unroll 1
  for (int r = 0; r < CH; ++r) {
    buf[0][r][ln] = bz;
    buf[1][r][ln] = bz;
  }

  // ---- layer-0 projection weights (uniform -> scalar regs), pre-scaled ----
  float w[4][16], pb[4];
  {
    const float sc[4] = {NL2E, NL2E, P2L2E, NL2E};
#pragma unroll
    for (int g = 0; g < 4; ++g) {
      pb[g] = sc[g] * (b_ih[g] + b_hh[g]);
#pragma unroll
      for (int d = 0; d < 16; ++d) w[g][d] = sc[g] * w_ih0[g * 16 + d];
    }
  }

  const float4* x4 = (const float4*)x;
  float4 xs[8];  // x for (eP, t=tq) [0..3] and (eP, t=tq+16) [4..7]
  float h = 0.f, c = 0.f;
  float2 pA[8], pB[8];

  // load half hf of chunk ci: 4 float4 = full 64 B row of (bW+eP, t)
  auto LOADH = [&](int ci, int hf) {
    const size_t base =
        ((size_t)(bW + eP) * Tn + (size_t)(ci * CH + tq + 16 * hf)) * 4;
#pragma unroll
    for (int i = 0; i < 4; ++i) xs[hf * 4 + i] = x4[base + i];
  };
  // project half hf (t = tq + 16*hf) into buffer bi, writing parity slots
  auto PROJH = [&](int bi, int hf) {
    float s0 = pb[0], s1 = pb[1], s2 = pb[2], s3 = pb[3];
#pragma unroll
    for (int i = 0; i < 4; ++i) {
      const float4 a = xs[hf * 4 + i];
      s0 = fmaf(a.x, w[0][i * 4 + 0], s0); s0 = fmaf(a.y, w[0][i * 4 + 1], s0);
      s0 = fmaf(a.z, w[0][i * 4 + 2], s0); s0 = fmaf(a.w, w[0][i * 4 + 3], s0);
      s1 = fmaf(a.x, w[1][i * 4 + 0], s1); s1 = fmaf(a.y, w[1][i * 4 + 1], s1);
      s1 = fmaf(a.z, w[1][i * 4 + 2], s1); s1 = fmaf(a.w, w[1][i * 4 + 3], s1);
      s2 = fmaf(a.x, w[2][i * 4 + 0], s2); s2 = fmaf(a.y, w[2][i * 4 + 1], s2);
      s2 = fmaf(a.z, w[2][i * 4 + 2], s2); s2 = fmaf(a.w, w[2][i * 4 + 3], s2);
      s3 = fmaf(a.x, w[3][i * 4 + 0], s3); s3 = fmaf(a.y, w[3][i * 4 + 1], s3);
      s3 = fmaf(a.z, w[3][i * 4 + 2], s3); s3 = fmaf(a.w, w[3][i * 4 + 3], s3);
    }
    const int r = tq + 16 * hf;
    buf[bi][r][eP * 16 + 0] = make_float2(s0, s2);  // even pair slot: (i, g)
    buf[bi][r][eP * 16 + 1] = make_float2(s1, s3);  // odd pair slot:  (f, o)
  };
  // bulk LDS->reg for one 8-tick block: 8 ds_read_b64, slot = own lane
  auto RD = [&](float2* p, int bi, int jb) {
#pragma unroll
    for (int k = 0; k < 8; ++k) p[k] = buf[bi][jb * 8 + k][ln];
  };
  auto T8 = [&](float2* p) {
#pragma unroll
    for (int k = 0; k < 8; ++k)
      tick<false>(h, c, p[k], wih, whh, podd, 0u, 0u);
  };
  auto T8g = [&](float2* p, unsigned tau0) {
#pragma unroll
    for (int k = 0; k < 8; ++k)
      tick<true>(h, c, p[k], wih, whh, podd, tau0 + (unsigned)k, l);
  };

  // ---- prologue: chunk 0 -> buf[0]; xs = chunk 1; pA = block 0 ----
  LOADH(0, 0); LOADH(0, 1);
  PROJH(0, 0); PROJH(0, 1);
  LOADH(1, 0); LOADH(1, 1);
  RD(pA, 0, 0);

  // ---- chunk 0 (block 0 gated for pipeline fill) ----
  RD(pB, 0, 1);  T8g(pA, 0u);  PROJH(1, 0);   // chunk 1 -> buf[1] rows 0..15
  RD(pA, 0, 2);  T8(pB);       PROJH(1, 1);   // rows 16..31
  RD(pB, 0, 3);  T8(pA);       LOADH(2, 0);
  RD(pA, 1, 0);  T8(pB);       LOADH(2, 1);

  // ---- chunks 1..15 (entry invariant: pA holds block 0 of chunk j) ----
#pragma unroll 1
  for (int j = 1; j < NCH; ++j) {
    const int cur = j & 1, nxt = cur ^ 1;
    const bool mp = (j < NCH - 1);  // project chunk j+1?
    const bool ml = (j < NCH - 2);  // load chunk j+2?
    RD(pB, cur, 1);  T8(pA);  if (mp) PROJH(nxt, 0);
    RD(pA, cur, 2);  T8(pB);  if (mp) PROJH(nxt, 1);
    RD(pB, cur, 3);  T8(pA);  if (ml) LOADH(j + 2, 0);
    RD(pA, mp ? nxt : cur, 0);  T8(pB);  if (ml) LOADH(j + 2, 1);
  }

  // ---- tail: 5 gated ticks (tau=512..516); non-leader slots hold bias,
  // leader lanes are inactive (act=false) ----
#pragma unroll
  for (unsigned k = 0; k < 5; ++k)
    tick<true>(h, c, pA[k], wih, whh, podd, 512u + k, l);

  if (rlane == 10) out[bW + eT] = h;  // layer 5 even lane; H=1 -> h itself
}

extern "C" void kernel_launch(void* const* d_in, const int* in_sizes, int n_in,
                              void* d_out, int out_size, void* d_ws, size_t ws_size,
                              hipStream_t stream) {
  (void)in_sizes; (void)n_in; (void)out_size; (void)d_ws; (void)ws_size;
  const float* x         = (const float*)d_in[0];
  const float* w_ih0     = (const float*)d_in[1];
  const float* w_ih_rest = (const float*)d_in[2];
  const float* w_hh      = (const float*)d_in[3];
  const float* b_ih      = (const float*)d_in[4];
  const float* b_hh      = (const float*)d_in[5];
  float* out = (float*)d_out;

  lstm_fused_kernel<<<Bn / 4, 64, 0, stream>>>(x, w_ih0, w_ih_rest, w_hh,
                                               b_ih, b_hh, out);
}

// Round 14
// 45.768 us; speedup vs baseline: 1.5156x; 1.0030x over previous
//
#include <hip/hip_runtime.h>

constexpr int Tn = 512;       // seq len
constexpr int Bn = 4096;      // batch
constexpr int CH = 32;        // timesteps per chunk
constexpr int NCH = Tn / CH;  // 16

// Gates are PRE-SCALED by folding into weights/biases: i,f,o by -log2e
// (sigmoid), g by +2*log2e (tanh). Cell c is carried scaled by +2*log2e.
constexpr float NL2E = -1.44269504088896340736f;
constexpr float P2L2E = 2.88539008177792681472f;

typedef float f2 __attribute__((ext_vector_type(2)));

#if defined(__has_builtin)
#if __has_builtin(__builtin_amdgcn_exp2f)
#define EXP2F(x) __builtin_amdgcn_exp2f(x)
#else
#define EXP2F(x) exp2f(x)
#endif
#else
#define EXP2F(x) exp2f(x)
#endif

// quad_perm [0,0,2,2]: both lanes of a pair get the EVEN lane's value
__device__ __forceinline__ float dpp_pair_even(float v) {
  return __int_as_float(__builtin_amdgcn_update_dpp(
      __float_as_int(v), __float_as_int(v), 0xA0, 0xf, 0xf, false));
}
// quad_perm [1,1,3,3]: both lanes of a pair get the ODD lane's value
__device__ __forceinline__ float dpp_pair_odd(float v) {
  return __int_as_float(__builtin_amdgcn_update_dpp(
      __float_as_int(v), __float_as_int(v), 0xF5, 0xf, 0xf, false));
}
// row_shr:2 within 16-lane rows: lane i <- lane i-2 (lanes 0,1 keep old)
__device__ __forceinline__ float dpp_shr2(float v) {
  return __int_as_float(__builtin_amdgcn_update_dpp(
      __float_as_int(v), __float_as_int(v), 0x112, 0xf, 0xf, false));
}

// One LSTM tick, cell split across a lane pair. Even lane: gates A=i, B=g;
// odd lane: A=f, B=o. Both lanes carry a VALID h (cell epilogue runs on the
// broadcast cn in both lanes), so the tick front-end needs only ONE dpp.
//   c'_s = [c_s*P + 2l2e*(Eg-1)*Q] * rcp(Q*P)   (P=(1+Ei)(1+Eg), Q=1+Ef)
//   h    = sig_o * (1 - 2*rcp(1+2^c'_s)),  sig_o = rcp(1+Eo) (odd's rcp)
template <bool GATED>
__device__ __forceinline__ void tick(float& h, float& c, const f2 pre,
                                     const f2 wih, const f2 whh,
                                     bool podd, unsigned tau, unsigned l) {
  const float h_in = dpp_shr2(h);        // prev pair's h (both lanes valid)
  const f2 hh2 = {h, h};
  const f2 hi2 = {h_in, h_in};
  const f2 tv = __builtin_elementwise_fma(hh2, whh, pre);   // v_pk_fma_f32
  const f2 av = __builtin_elementwise_fma(hi2, wih, tv);    // v_pk_fma_f32
  const float EA = EXP2F(av.x);          // even: Ei ; odd: Ef
  const float EB = EXP2F(av.y);          // even: Eg ; odd: Eo
  const f2 sv = (f2){EA, EB} + (f2){1.0f, 1.0f};            // v_pk_add_f32
  const float sA = sv.x;                 // even: u=1+Ei ; odd: Q=1+Ef
  const float sB = sv.y;                 // even: v=1+Eg ; odd: 1+Eo
  const float m = sA * sB;               // even: P
  const float Qx = dpp_pair_odd(sA);     // Q to both lanes
  const float qm = Qx * m;               // even: Q*P
  const float rin = podd ? sB : qm;
  const float RC = __builtin_amdgcn_rcpf(rin);  // even: R ; odd: sig_o
  const float sgo = dpp_pair_odd(RC);    // sig_o to both lanes
  const float ws = fmaf(P2L2E, EB, -P2L2E);  // even: 2l2e*(Eg-1)
  const float wsQ = ws * Qx;
  const float num = fmaf(c, m, wsQ);     // even: c*P + ws*Q
  const float cn = num * RC;             // even: new scaled cell
  const float cnb = dpp_pair_even(cn);   // broadcast cell to the pair
  const float Ec = EXP2F(cnb);           // Inf-safe: Ec=Inf -> th -> 1
  const float t2 = 1.0f + Ec;
  const float rt = __builtin_amdgcn_rcpf(t2);
  const float th = fmaf(-2.0f, rt, 1.0f);  // tanh(c)
  const float hn = sgo * th;             // valid in BOTH lanes
  if (GATED) {
    const bool act = (tau - l) < (unsigned)Tn;  // unsigned wrap: tau<l off
    c = act ? cn : c;
    h = act ? hn : h;
  } else {
    c = cn;
    h = hn;
  }
}

// Fused layer-0 projection + 6-layer systolic recurrence, 16 lanes/element
// (lane pair per layer). 1024 single-wave blocks -> 4 blocks/CU, all SIMDs.
// LDS: unified [2][32 rows][64 slots] float2; slot=lane. Leader-pair slots
// hold projections (rewritten per chunk); all other slots hold that lane's
// replicated gate bias (written once) -> 1 ds_read_b64/tick, no mask ops.
__global__ __launch_bounds__(64, 1) void lstm_fused_kernel(
    const float* __restrict__ x, const float* __restrict__ w_ih0,
    const float* __restrict__ w_ih_rest, const float* __restrict__ w_hh,
    const float* __restrict__ b_ih, const float* __restrict__ b_hh,
    float* __restrict__ out) {
  __shared__ __align__(16) float2 buf[2][CH][64];  // 32 KB

  const int ln = threadIdx.x;
  const int bW = blockIdx.x * 4;   // 4 elements per wave
  // tick-phase roles
  const int eT = ln >> 4;          // element (16-lane row)
  const int rlane = ln & 15;
  const unsigned l = (unsigned)(rlane >> 1);  // layer (active l<6)
  const bool podd = (rlane & 1) != 0;
  // proj-phase roles
  const int eP = ln & 3;           // element
  const int tq = ln >> 2;          // t sub-index 0..15

  // ---- per-lane recurrence weights (pre-scaled) ----
  const int lc = (l < 6) ? (int)l : 5;
  const int gA = podd ? 1 : 0;     // even: i, odd: f   (both -l2e scale)
  const int gB = podd ? 3 : 2;     // even: g (+2l2e), odd: o (-l2e)
  const float scB = podd ? NL2E : P2L2E;
  f2 whh = {NL2E * w_hh[lc * 4 + gA], scB * w_hh[lc * 4 + gB]};
  f2 wih = {0.f, 0.f};
  float2 bz = make_float2(0.f, 0.f);
  if (l >= 1 && l < 6) {
    wih = (f2){NL2E * w_ih_rest[(lc - 1) * 4 + gA],
               scB * w_ih_rest[(lc - 1) * 4 + gB]};
    bz = make_float2(NL2E * (b_ih[l * 4 + gA] + b_hh[l * 4 + gA]),
                     scB * (b_ih[l * 4 + gB] + b_hh[l * 4 + gB]));
  }
  if (l >= 6) whh = (f2){0.f, 0.f};  // inert lanes

  // ---- bias fill: every row of both buffers, own slot (once) ----
#pragma unroll 1
  for (int r = 0; r < CH; ++r) {
    buf[0][r][ln] = bz;
    buf[1][r][ln] = bz;
  }

  // ---- layer-0 projection weights (uniform -> scalar regs), pre-scaled ----
  float w[4][16], pb[4];
  {
    const float sc[4] = {NL2E, NL2E, P2L2E, NL2E};
#pragma unroll
    for (int g = 0; g < 4; ++g) {
      pb[g] = sc[g] * (b_ih[g] + b_hh[g]);
#pragma unroll
      for (int d = 0; d < 16; ++d) w[g][d] = sc[g] * w_ih0[g * 16 + d];
    }
  }

  const float4* x4 = (const float4*)x;
  float4 xs[8];  // x for (eP, t=tq) [0..3] and (eP, t=tq+16) [4..7]
  float h = 0.f, c = 0.f;
  f2 pA[8], pB[8];

  // load half hf of chunk ci: 4 float4 = full 64 B row of (bW+eP, t)
  auto LOADH = [&](int ci, int hf) {
    const size_t base =
        ((size_t)(bW + eP) * Tn + (size_t)(ci * CH + tq + 16 * hf)) * 4;
#pragma unroll
    for (int i = 0; i < 4; ++i) xs[hf * 4 + i] = x4[base + i];
  };
  // project half hf (t = tq + 16*hf) into buffer bi, writing parity slots
  auto PROJH = [&](int bi, int hf) {
    float s0 = pb[0], s1 = pb[1], s2 = pb[2], s3 = pb[3];
#pragma unroll
    for (int i = 0; i < 4; ++i) {
      const float4 a = xs[hf * 4 + i];
      s0 = fmaf(a.x, w[0][i * 4 + 0], s0); s0 = fmaf(a.y, w[0][i * 4 + 1], s0);
      s0 = fmaf(a.z, w[0][i * 4 + 2], s0); s0 = fmaf(a.w, w[0][i * 4 + 3], s0);
      s1 = fmaf(a.x, w[1][i * 4 + 0], s1); s1 = fmaf(a.y, w[1][i * 4 + 1], s1);
      s1 = fmaf(a.z, w[1][i * 4 + 2], s1); s1 = fmaf(a.w, w[1][i * 4 + 3], s1);
      s2 = fmaf(a.x, w[2][i * 4 + 0], s2); s2 = fmaf(a.y, w[2][i * 4 + 1], s2);
      s2 = fmaf(a.z, w[2][i * 4 + 2], s2); s2 = fmaf(a.w, w[2][i * 4 + 3], s2);
      s3 = fmaf(a.x, w[3][i * 4 + 0], s3); s3 = fmaf(a.y, w[3][i * 4 + 1], s3);
      s3 = fmaf(a.z, w[3][i * 4 + 2], s3); s3 = fmaf(a.w, w[3][i * 4 + 3], s3);
    }
    const int r = tq + 16 * hf;
    buf[bi][r][eP * 16 + 0] = make_float2(s0, s2);  // even pair slot: (i, g)
    buf[bi][r][eP * 16 + 1] = make_float2(s1, s3);  // odd pair slot:  (f, o)
  };
  // bulk LDS->reg for one 8-tick block: 8 ds_read_b64, slot = own lane
  auto RD = [&](f2* p, int bi, int jb) {
#pragma unroll
    for (int k = 0; k < 8; ++k) {
      const float2 v = buf[bi][jb * 8 + k][ln];
      p[k] = (f2){v.x, v.y};
    }
  };
  auto T8 = [&](f2* p) {
#pragma unroll
    for (int k = 0; k < 8; ++k)
      tick<false>(h, c, p[k], wih, whh, podd, 0u, 0u);
  };
  auto T8g = [&](f2* p, unsigned tau0) {
#pragma unroll
    for (int k = 0; k < 8; ++k)
      tick<true>(h, c, p[k], wih, whh, podd, tau0 + (unsigned)k, l);
  };

  // ---- prologue: chunk 0 -> buf[0]; xs = chunk 1; pA = block 0 ----
  LOADH(0, 0); LOADH(0, 1);
  PROJH(0, 0); PROJH(0, 1);
  LOADH(1, 0); LOADH(1, 1);
  RD(pA, 0, 0);

  // ---- chunk 0 (block 0 gated for pipeline fill) ----
  RD(pB, 0, 1);  T8g(pA, 0u);  PROJH(1, 0);   // chunk 1 -> buf[1] rows 0..15
  RD(pA, 0, 2);  T8(pB);       PROJH(1, 1);   // rows 16..31
  RD(pB, 0, 3);  T8(pA);       LOADH(2, 0);
  RD(pA, 1, 0);  T8(pB);       LOADH(2, 1);

  // ---- chunks 1..15 (entry invariant: pA holds block 0 of chunk j) ----
#pragma unroll 1
  for (int j = 1; j < NCH; ++j) {
    const int cur = j & 1, nxt = cur ^ 1;
    const bool mp = (j < NCH - 1);  // project chunk j+1?
    const bool ml = (j < NCH - 2);  // load chunk j+2?
    RD(pB, cur, 1);  T8(pA);  if (mp) PROJH(nxt, 0);
    RD(pA, cur, 2);  T8(pB);  if (mp) PROJH(nxt, 1);
    RD(pB, cur, 3);  T8(pA);  if (ml) LOADH(j + 2, 0);
    RD(pA, mp ? nxt : cur, 0);  T8(pB);  if (ml) LOADH(j + 2, 1);
  }

  // ---- tail: 5 gated ticks (tau=512..516); non-leader slots hold bias,
  // leader lanes are inactive (act=false) ----
#pragma unroll
  for (unsigned k = 0; k < 5; ++k)
    tick<true>(h, c, pA[k], wih, whh, podd, 512u + k, l);

  if (rlane == 10) out[bW + eT] = h;  // layer 5 even lane; H=1 -> h itself
}

extern "C" void kernel_launch(void* const* d_in, const int* in_sizes, int n_in,
                              void* d_out, int out_size, void* d_ws, size_t ws_size,
                              hipStream_t stream) {
  (void)in_sizes; (void)n_in; (void)out_size; (void)d_ws; (void)ws_size;
  const float* x         = (const float*)d_in[0];
  const float* w_ih0     = (const float*)d_in[1];
  const float* w_ih_rest = (const float*)d_in[2];
  const float* w_hh      = (const float*)d_in[3];
  const float* b_ih      = (const float*)d_in[4];
  const float* b_hh      = (const float*)d_in[5];
  float* out = (float*)d_out;

  lstm_fused_kernel<<<Bn / 4, 64, 0, stream>>>(x, w_ih0, w_ih_rest, w_hh,
                                               b_ih, b_hh, out);
}